// Round 7
// baseline (943.143 us; speedup 1.0000x reference)
//
#include <hip/hip_runtime.h>
#include <stdint.h>

#define BATCH 8192
#define DIM   1024            // elements per row; fp8 => also bytes per row
#define NTILE 64              // 8192 / 128 tiles per dimension
#define MAXB  292             // max tiles per XCD band
#define GRIDX (8 * MAXB)      // padded x-grid; blocks past band size exit
#define TILEB (128 * 128)     // LDS bytes per tile buffer

#define FSCALE 8.0f                          // pre-scale before fp8 quant
#define EXPF   (2.0f / (FSCALE * FSCALE))    // exp(2*dot) = exp(acc * EXPF)

typedef int   intx4   __attribute__((ext_vector_type(4)));
typedef int   intx8   __attribute__((ext_vector_type(8)));
typedef float floatx4 __attribute__((ext_vector_type(4)));

__device__ __forceinline__ void async_ld16(const void* g, void* l) {
    __builtin_amdgcn_global_load_lds(
        (__attribute__((address_space(1))) void*)(void*)g,
        (__attribute__((address_space(3))) void*)l,
        16, 0, 0);
}

// ------------- row L2-normalize: fp32 -> fp8 e4m3 (x FSCALE) -------------
__global__ __launch_bounds__(256) void norm_kernel(const float* __restrict__ text,
                                                   const float* __restrict__ image,
                                                   unsigned char* __restrict__ out) {
    const int fsel = blockIdx.y;
    const float* in = fsel ? image : text;
    unsigned char* o = out + (size_t)fsel * BATCH * DIM;
    const int row = blockIdx.x;
    const int t   = threadIdx.x;
    const float4* src = (const float4*)(in + (size_t)row * DIM);
    float4 v = src[t];
    float ss = v.x * v.x + v.y * v.y + v.z * v.z + v.w * v.w;
    #pragma unroll
    for (int m = 32; m >= 1; m >>= 1) ss += __shfl_xor(ss, m);
    __shared__ float red[4];
    if ((t & 63) == 0) red[t >> 6] = ss;
    __syncthreads();
    const float n2  = red[0] + red[1] + red[2] + red[3];
    const float inv = FSCALE / fmaxf(sqrtf(n2), 1e-12f);
    // pack 4 e4m3 bytes (gfx950: OCP e4m3fn), byte i = element t*4+i
    int p = __builtin_amdgcn_cvt_pk_fp8_f32(v.x * inv, v.y * inv, 0, false);
    p     = __builtin_amdgcn_cvt_pk_fp8_f32(v.z * inv, v.w * inv, p, true);
    ((int*)(o + (size_t)row * DIM))[t] = p;
}

// -------- fused symmetric sim GEMM (MX-fp8, unit scales) + exp + dual sum --------
// 512 threads / 8 waves; per-wave 64x32 sub-tile (4 mi x 2 ni of 16x16).
// amdgpu_waves_per_eu(4): VGPR budget 128 (demand ~105) -> 4 waves/SIMD.
// K-loop order: [barrier][read frags][issue next tile][mfma] so conservative
// vmcnt waits before ds_read target loads issued a FULL iteration earlier
// (r4 vs r6 identical timings proved the old issue-then-read order was
// serialized by a compiler-inserted vmcnt(0) before the reads).
__global__ __launch_bounds__(512) __attribute__((amdgpu_waves_per_eu(4)))
void sim_kernel(const unsigned char* __restrict__ F,
                const int* __restrict__ label,
                float* __restrict__ S) {
    // band tables: bj in [bs[x], be[x]); bn[x] = tiles in band
    const int bs[8] = {0, 23, 32, 40, 46, 51, 56, 60};
    const int be[8] = {23, 32, 40, 46, 51, 56, 60, 64};
    const int bn[8] = {276, 252, 292, 261, 245, 270, 234, 250};

    const int x = blockIdx.x & 7;       // XCD (round-robin dispatch heuristic)
    const int l = blockIdx.x >> 3;      // local index within band
    if (l >= bn[x]) return;             // padding block

    const int s = bs[x];
    const int w = be[x] - s;
    int bi, bj;
    const int nfull = s * w;
    if (l < nfull) {
        bi = l / w;
        bj = s + (l % w);
    } else {
        int l2 = l - nfull;
        int k = 0, width = w;
        while (l2 >= width) { l2 -= width; --width; ++k; }
        bi = s + k;
        bj = bi + l2;
    }
    const bool diag = (bi == bj);

    const int f = blockIdx.z;
    const unsigned char* A = F + (size_t)f * BATCH * DIM;
    float* SR = S + (size_t)f * 2 * BATCH;
    float* SN = SR + BATCH;

    const int rowTile = bi * 128;
    const int colTile = bj * 128;

    // double-buffered 128x128-byte tiles; 16-B chunk swizzle: chunk c of row r
    // stored at slot c ^ (r&7).
    __shared__ __align__(16) unsigned char As[2 * TILEB];
    __shared__ __align__(16) unsigned char Bs[2 * TILEB];

    const int tid  = threadIdx.x;
    const int lane = tid & 63;
    const int wave = tid >> 6;          // 0..7
    const int wm   = wave >> 2;         // 0..1: 64-row stripe
    const int wn   = wave & 3;          // 0..3: 32-col stripe
    const int quad = lane >> 4;
    const int cl   = lane & 15;

    // staging: wave w covers rows [w*16, w*16+16) of A and B tiles;
    // issue t covers rows w*16+t*8..+8; lane -> row lane>>3, LDS slot lane&7
    // (HW: dest = base + lane*16), global chunk = slot ^ (row&7)
    const int sRowOff = lane >> 3;            // 0..7
    const int chunk   = (lane & 7) ^ sRowOff; // (row&7) == sRowOff
    const unsigned char* gA = A + (size_t)(rowTile + wave * 16 + sRowOff) * DIM + chunk * 16;
    const unsigned char* gB = A + (size_t)(colTile + wave * 16 + sRowOff) * DIM + chunk * 16;
    const int lOff = wave * 16 * 128 + lane * 16;   // within a tile buffer

    floatx4 acc[4][2];
    const floatx4 z4 = {0.f, 0.f, 0.f, 0.f};
    #pragma unroll
    for (int mi = 0; mi < 4; ++mi)
        #pragma unroll
        for (int ni = 0; ni < 2; ++ni) acc[mi][ni] = z4;

    // frag read slots (un-swizzle): lane reads 16-B chunks 2q, 2q+1 of its row;
    // row&7 == cl&7 for all frag rows (offsets are multiples of 16)
    const int h  = cl & 7;
    const int s0 = ((2 * quad) ^ h) * 16;
    const int s1 = ((2 * quad + 1) ^ h) * 16;
    const int aRowOff = (wm * 64 + cl) * 128;       // within a tile buffer
    const int bRowOff = (wn * 32 + cl) * 128;

    // preload tile 0 into buffer 0 (2 issues A + 2 issues B per wave)
    #pragma unroll
    for (int t = 0; t < 2; ++t) {
        async_ld16(gA + (size_t)t * 8 * DIM, As + lOff + t * 1024);
        async_ld16(gB + (size_t)t * 8 * DIM, Bs + lOff + t * 1024);
    }
    gA += 128; gB += 128;

    for (int k0 = 0; k0 < DIM; k0 += 128) {
        const int cur = (k0 >> 7) & 1;
        __syncthreads();   // buffer `cur` fully populated (vmcnt drained here)

        const unsigned char* aRow = As + cur * TILEB + aRowOff;
        const unsigned char* bRow = Bs + cur * TILEB + bRowOff;

        // 1) read ALL fragments of the current buffer
        intx8 af[4], bf[2];
        #pragma unroll
        for (int mi = 0; mi < 4; ++mi) {
            const unsigned char* r = aRow + mi * 16 * 128;
            intx4 lo = *(const intx4*)(r + s0);
            intx4 hi = *(const intx4*)(r + s1);
            af[mi] = __builtin_shufflevector(lo, hi, 0, 1, 2, 3, 4, 5, 6, 7);
        }
        #pragma unroll
        for (int ni = 0; ni < 2; ++ni) {
            const unsigned char* r = bRow + ni * 16 * 128;
            intx4 lo = *(const intx4*)(r + s0);
            intx4 hi = *(const intx4*)(r + s1);
            bf[ni] = __builtin_shufflevector(lo, hi, 0, 1, 2, 3, 4, 5, 6, 7);
        }

        // 2) THEN issue next tile into the idle buffer (loads get the whole
        //    MFMA block + next barrier to land)
        if (k0 + 128 < DIM) {
            const int nxt = cur ^ 1;
            #pragma unroll
            for (int t = 0; t < 2; ++t) {
                async_ld16(gA + (size_t)t * 8 * DIM, As + nxt * TILEB + lOff + t * 1024);
                async_ld16(gB + (size_t)t * 8 * DIM, Bs + nxt * TILEB + lOff + t * 1024);
            }
            gA += 128; gB += 128;
        }

        // 3) MFMAs
        #pragma unroll
        for (int mi = 0; mi < 4; ++mi)
            #pragma unroll
            for (int ni = 0; ni < 2; ++ni)
                acc[mi][ni] = __builtin_amdgcn_mfma_scale_f32_16x16x128_f8f6f4(
                    af[mi], bf[ni], acc[mi][ni],
                    0, 0,                     // cbsz=fp8(e4m3), blgp=fp8(e4m3)
                    0, 0x7F7F7F7F,            // scale_a opsel, scale_a = 2^0
                    0, 0x7F7F7F7F);           // scale_b opsel, scale_b = 2^0
    }

    // ---- epilogue: e = exp(acc * 2/FSCALE^2), eye mask, dual row/col sums ----
    int   colg[2];
    float wRc[2];                        // col label weight (row-part bucket)
    #pragma unroll
    for (int ni = 0; ni < 2; ++ni) {
        colg[ni] = colTile + wn * 32 + ni * 16 + cl;
        wRc[ni]  = (label[colg[ni]] != 0) ? 1.0f : 0.0f;
    }

    float colR[2] = {0.f, 0.f};
    float colN[2] = {0.f, 0.f};

    #pragma unroll
    for (int mi = 0; mi < 4; ++mi) {
        const int rowBase = rowTile + wm * 64 + mi * 16 + quad * 4;   // C/D: row=quad*4+reg
        #pragma unroll
        for (int r = 0; r < 4; ++r) {
            const int rowg = rowBase + r;
            const float wRr = (label[rowg] != 0) ? 1.0f : 0.0f;
            float pR = 0.f, pN = 0.f;
            #pragma unroll
            for (int ni = 0; ni < 2; ++ni) {
                float c = acc[mi][ni][r];
                float e = __expf(c * EXPF);
                if (diag) e = (rowg == colg[ni]) ? 0.0f : e;      // eye mask
                pR += wRc[ni] * e;
                pN += (1.0f - wRc[ni]) * e;
                colR[ni] += wRr * e;
                colN[ni] += (1.0f - wRr) * e;
            }
            #pragma unroll
            for (int m = 1; m < 16; m <<= 1) {
                pR += __shfl_xor(pR, m);
                pN += __shfl_xor(pN, m);
            }
            if (cl == 0) {
                atomicAdd(&SR[rowg], pR);
                atomicAdd(&SN[rowg], pN);
            }
        }
    }

    if (!diag) {
        #pragma unroll
        for (int ni = 0; ni < 2; ++ni) {
            float cR = colR[ni], cN = colN[ni];
            cR += __shfl_xor(cR, 16); cN += __shfl_xor(cN, 16);
            cR += __shfl_xor(cR, 32); cN += __shfl_xor(cN, 32);
            if (quad == 0) {
                atomicAdd(&SR[colg[ni]], cR);
                atomicAdd(&SN[colg[ni]], cN);
            }
        }
    }
}

// ---------------- final per-row loss + global reduce ----------------
__global__ __launch_bounds__(256) void loss_kernel(const float* __restrict__ S,
                                                   const int* __restrict__ label,
                                                   float* __restrict__ out) {
    const int i = blockIdx.x * 256 + threadIdx.x;   // 0..8191
    const int lab = label[i];
    float t = 0.f;
    #pragma unroll
    for (int f = 0; f < 2; ++f) {
        const float* SR = S + (size_t)f * 2 * BATCH;
        const float* SN = SR + BATCH;
        const float own = lab ? SR[i] : SN[i];
        const float oth = lab ? SN[i] : SR[i];
        t += -logf(own / (own + oth) + 1e-8f);
    }
    t *= (1.0f / 4096.0f);
    #pragma unroll
    for (int m = 32; m >= 1; m >>= 1) t += __shfl_xor(t, m);
    __shared__ float red[4];
    if ((threadIdx.x & 63) == 0) red[threadIdx.x >> 6] = t;
    __syncthreads();
    if (threadIdx.x == 0) atomicAdd(out, red[0] + red[1] + red[2] + red[3]);
}

extern "C" void kernel_launch(void* const* d_in, const int* in_sizes, int n_in,
                              void* d_out, int out_size, void* d_ws, size_t ws_size,
                              hipStream_t stream) {
    const float* text  = (const float*)d_in[0];
    const float* image = (const float*)d_in[1];
    const int*   label = (const int*)d_in[2];
    float* out = (float*)d_out;

    // workspace: Fn[2][8192][1024] fp8 (16 MB), then S[2][2][8192] f32
    unsigned char* Fn = (unsigned char*)d_ws;
    float* S = (float*)((char*)d_ws + (size_t)2 * BATCH * DIM);

    hipMemsetAsync(S, 0, (size_t)2 * 2 * BATCH * sizeof(float), stream);
    hipMemsetAsync(out, 0, sizeof(float), stream);

    dim3 ngrid(BATCH, 2);
    norm_kernel<<<ngrid, 256, 0, stream>>>(text, image, Fn);

    dim3 grid(GRIDX, 1, 2);
    sim_kernel<<<grid, 512, 0, stream>>>(Fn, label, S);

    loss_kernel<<<BATCH / 256, 256, 0, stream>>>(S, label, out);
}

// Round 8
// 740.404 us; speedup vs baseline: 1.2738x; 1.2738x over previous
//
#include <hip/hip_runtime.h>
#include <stdint.h>

#define BATCH 8192
#define DIM   1024            // elements per row; fp8 => also bytes per row
#define NTILE 64              // 8192 / 128 tiles per dimension
#define MAXB  292             // max tiles per XCD band
#define GRIDX (8 * MAXB)      // padded x-grid; blocks past band size exit

#define FSCALE 8.0f                          // pre-scale before fp8 quant
#define EXPF   (2.0f / (FSCALE * FSCALE))    // exp(2*dot) = exp(acc * EXPF)

typedef int   intx4   __attribute__((ext_vector_type(4)));
typedef int   intx8   __attribute__((ext_vector_type(8)));
typedef float floatx4 __attribute__((ext_vector_type(4)));

// ------------- row L2-normalize: fp32 -> fp8 e4m3 (x FSCALE) -------------
__global__ __launch_bounds__(256) void norm_kernel(const float* __restrict__ text,
                                                   const float* __restrict__ image,
                                                   unsigned char* __restrict__ out) {
    const int fsel = blockIdx.y;
    const float* in = fsel ? image : text;
    unsigned char* o = out + (size_t)fsel * BATCH * DIM;
    const int row = blockIdx.x;
    const int t   = threadIdx.x;
    const float4* src = (const float4*)(in + (size_t)row * DIM);
    float4 v = src[t];
    float ss = v.x * v.x + v.y * v.y + v.z * v.z + v.w * v.w;
    #pragma unroll
    for (int m = 32; m >= 1; m >>= 1) ss += __shfl_xor(ss, m);
    __shared__ float red[4];
    if ((t & 63) == 0) red[t >> 6] = ss;
    __syncthreads();
    const float n2  = red[0] + red[1] + red[2] + red[3];
    const float inv = FSCALE / fmaxf(sqrtf(n2), 1e-12f);
    // pack 4 e4m3 bytes (gfx950: OCP e4m3fn), byte i = element t*4+i
    int p = __builtin_amdgcn_cvt_pk_fp8_f32(v.x * inv, v.y * inv, 0, false);
    p     = __builtin_amdgcn_cvt_pk_fp8_f32(v.z * inv, v.w * inv, p, true);
    ((int*)(o + (size_t)row * DIM))[t] = p;
}

// -------- fused symmetric sim GEMM (MX-fp8, unit scales) + exp + dual sum --------
// BARRIER-FREE K-loop: no LDS. Each lane loads its MFMA fragment bytes
// directly global->VGPR (two dwordx4 per fragment: row(cl)*DIM + k0 + quad*32).
// Explicit 2-stage software pipeline (fragment double-buffer in registers):
// loads for tile k+128 are issued before the MFMAs of tile k, so the
// compiler's fine-grained s_waitcnt vmcnt(N) gives each load a full MFMA
// block (~550 cyc) to land. This is the AITER-style restructure -- the
// global_load_lds + vmcnt(0) + barrier chain (r4/r6, both 267 us) is gone.
// NOTE (r5, r7): no occupancy attributes -- forcing VGPR budgets below
// demand spills accumulators (1.5-3.6 GB scratch traffic). Natural alloc.
__global__ __launch_bounds__(512)
void sim_kernel(const unsigned char* __restrict__ F,
                const int* __restrict__ label,
                float* __restrict__ S) {
    // band tables: bj in [bs[x], be[x]); bn[x] = tiles in band
    const int bs[8] = {0, 23, 32, 40, 46, 51, 56, 60};
    const int be[8] = {23, 32, 40, 46, 51, 56, 60, 64};
    const int bn[8] = {276, 252, 292, 261, 245, 270, 234, 250};

    const int x = blockIdx.x & 7;       // XCD (round-robin dispatch heuristic)
    const int l = blockIdx.x >> 3;      // local index within band
    if (l >= bn[x]) return;             // padding block

    const int s = bs[x];
    const int w = be[x] - s;
    int bi, bj;
    const int nfull = s * w;
    if (l < nfull) {
        bi = l / w;
        bj = s + (l % w);
    } else {
        int l2 = l - nfull;
        int k = 0, width = w;
        while (l2 >= width) { l2 -= width; --width; ++k; }
        bi = s + k;
        bj = bi + l2;
    }
    const bool diag = (bi == bj);

    const int f = blockIdx.z;
    const unsigned char* A = F + (size_t)f * BATCH * DIM;
    float* SR = S + (size_t)f * 2 * BATCH;
    float* SN = SR + BATCH;

    const int rowTile = bi * 128;
    const int colTile = bj * 128;

    const int tid  = threadIdx.x;
    const int lane = tid & 63;
    const int wave = tid >> 6;          // 0..7
    const int wm   = wave >> 2;         // 0..1: 64-row stripe
    const int wn   = wave & 3;          // 0..3: 32-col stripe
    const int quad = lane >> 4;
    const int cl   = lane & 15;

    // per-lane fragment base pointers: A-operand lane(q,cl) holds
    // A[m = cl][k = k0 + q*32 .. +32]  (layout verified by passing LDS kernels)
    const unsigned char* aBase = A + (size_t)(rowTile + wm * 64 + cl) * DIM + quad * 32;
    const unsigned char* bBase = A + (size_t)(colTile + wn * 32 + cl) * DIM + quad * 32;

    floatx4 acc[4][2];
    const floatx4 z4 = {0.f, 0.f, 0.f, 0.f};
    #pragma unroll
    for (int mi = 0; mi < 4; ++mi)
        #pragma unroll
        for (int ni = 0; ni < 2; ++ni) acc[mi][ni] = z4;

#define LOADF(AF, BF, K0)                                                       \
    {                                                                           \
        _Pragma("unroll")                                                       \
        for (int mi = 0; mi < 4; ++mi) {                                        \
            const unsigned char* p = aBase + (size_t)mi * 16 * DIM + (K0);      \
            intx4 lo = *(const intx4*)(p);                                      \
            intx4 hi = *(const intx4*)(p + 16);                                 \
            AF[mi] = __builtin_shufflevector(lo, hi, 0, 1, 2, 3, 4, 5, 6, 7);   \
        }                                                                       \
        _Pragma("unroll")                                                       \
        for (int ni = 0; ni < 2; ++ni) {                                        \
            const unsigned char* p = bBase + (size_t)ni * 16 * DIM + (K0);      \
            intx4 lo = *(const intx4*)(p);                                      \
            intx4 hi = *(const intx4*)(p + 16);                                 \
            BF[ni] = __builtin_shufflevector(lo, hi, 0, 1, 2, 3, 4, 5, 6, 7);   \
        }                                                                       \
    }

#define MFMAS(AF, BF)                                                           \
    {                                                                           \
        _Pragma("unroll")                                                       \
        for (int mi = 0; mi < 4; ++mi)                                          \
            _Pragma("unroll")                                                   \
            for (int ni = 0; ni < 2; ++ni)                                      \
                acc[mi][ni] = __builtin_amdgcn_mfma_scale_f32_16x16x128_f8f6f4( \
                    AF[mi], BF[ni], acc[mi][ni],                                \
                    0, 0,             /* cbsz, blgp = fp8 e4m3 */               \
                    0, 0x7F7F7F7F,    /* scale_a = 2^0 */                       \
                    0, 0x7F7F7F7F);   /* scale_b = 2^0 */                       \
    }

    intx8 afA[4], bfA[2], afB[4], bfB[2];
    LOADF(afA, bfA, 0)
    #pragma unroll
    for (int kk = 0; kk < DIM; kk += 256) {
        LOADF(afB, bfB, kk + 128)          // prefetch odd tile
        MFMAS(afA, bfA)                    // consume even tile
        if (kk + 256 < DIM) LOADF(afA, bfA, kk + 256)  // prefetch next even
        MFMAS(afB, bfB)                    // consume odd tile
    }

    // ---- epilogue: e = exp(acc * 2/FSCALE^2), eye mask, dual row/col sums ----
    int   colg[2];
    float wRc[2];                        // col label weight (row-part bucket)
    #pragma unroll
    for (int ni = 0; ni < 2; ++ni) {
        colg[ni] = colTile + wn * 32 + ni * 16 + cl;
        wRc[ni]  = (label[colg[ni]] != 0) ? 1.0f : 0.0f;
    }

    float colR[2] = {0.f, 0.f};
    float colN[2] = {0.f, 0.f};

    #pragma unroll
    for (int mi = 0; mi < 4; ++mi) {
        const int rowBase = rowTile + wm * 64 + mi * 16 + quad * 4;   // C/D: row=quad*4+reg
        #pragma unroll
        for (int r = 0; r < 4; ++r) {
            const int rowg = rowBase + r;
            const float wRr = (label[rowg] != 0) ? 1.0f : 0.0f;
            float pR = 0.f, pN = 0.f;
            #pragma unroll
            for (int ni = 0; ni < 2; ++ni) {
                float c = acc[mi][ni][r];
                float e = __expf(c * EXPF);
                if (diag) e = (rowg == colg[ni]) ? 0.0f : e;      // eye mask
                pR += wRc[ni] * e;
                pN += (1.0f - wRc[ni]) * e;
                colR[ni] += wRr * e;
                colN[ni] += (1.0f - wRr) * e;
            }
            #pragma unroll
            for (int m = 1; m < 16; m <<= 1) {
                pR += __shfl_xor(pR, m);
                pN += __shfl_xor(pN, m);
            }
            if (cl == 0) {
                atomicAdd(&SR[rowg], pR);
                atomicAdd(&SN[rowg], pN);
            }
        }
    }

    if (!diag) {
        #pragma unroll
        for (int ni = 0; ni < 2; ++ni) {
            float cR = colR[ni], cN = colN[ni];
            cR += __shfl_xor(cR, 16); cN += __shfl_xor(cN, 16);
            cR += __shfl_xor(cR, 32); cN += __shfl_xor(cN, 32);
            if (quad == 0) {
                atomicAdd(&SR[colg[ni]], cR);
                atomicAdd(&SN[colg[ni]], cN);
            }
        }
    }
}

// ---------------- final per-row loss + global reduce ----------------
__global__ __launch_bounds__(256) void loss_kernel(const float* __restrict__ S,
                                                   const int* __restrict__ label,
                                                   float* __restrict__ out) {
    const int i = blockIdx.x * 256 + threadIdx.x;   // 0..8191
    const int lab = label[i];
    float t = 0.f;
    #pragma unroll
    for (int f = 0; f < 2; ++f) {
        const float* SR = S + (size_t)f * 2 * BATCH;
        const float* SN = SR + BATCH;
        const float own = lab ? SR[i] : SN[i];
        const float oth = lab ? SN[i] : SR[i];
        t += -logf(own / (own + oth) + 1e-8f);
    }
    t *= (1.0f / 4096.0f);
    #pragma unroll
    for (int m = 32; m >= 1; m >>= 1) t += __shfl_xor(t, m);
    __shared__ float red[4];
    if ((threadIdx.x & 63) == 0) red[threadIdx.x >> 6] = t;
    __syncthreads();
    if (threadIdx.x == 0) atomicAdd(out, red[0] + red[1] + red[2] + red[3]);
}

extern "C" void kernel_launch(void* const* d_in, const int* in_sizes, int n_in,
                              void* d_out, int out_size, void* d_ws, size_t ws_size,
                              hipStream_t stream) {
    const float* text  = (const float*)d_in[0];
    const float* image = (const float*)d_in[1];
    const int*   label = (const int*)d_in[2];
    float* out = (float*)d_out;

    // workspace: Fn[2][8192][1024] fp8 (16 MB), then S[2][2][8192] f32
    unsigned char* Fn = (unsigned char*)d_ws;
    float* S = (float*)((char*)d_ws + (size_t)2 * BATCH * DIM);

    hipMemsetAsync(S, 0, (size_t)2 * 2 * BATCH * sizeof(float), stream);
    hipMemsetAsync(out, 0, sizeof(float), stream);

    dim3 ngrid(BATCH, 2);
    norm_kernel<<<ngrid, 256, 0, stream>>>(text, image, Fn);

    dim3 grid(GRIDX, 1, 2);
    sim_kernel<<<grid, 512, 0, stream>>>(Fn, label, S);

    loss_kernel<<<BATCH / 256, 256, 0, stream>>>(S, label, out);
}

// Round 9
// 427.679 us; speedup vs baseline: 2.2053x; 1.7312x over previous
//
#include <hip/hip_runtime.h>
#include <stdint.h>

#define BATCH 8192
#define DIM   1024            // elements per row; fp8 => also bytes per row
#define NTILE 64              // 8192 / 128 tiles per dimension
#define MAXB  292             // max tiles per XCD band
#define GRIDX (8 * MAXB)      // padded x-grid; blocks past band size exit
#define TILEB (128 * 128)     // LDS bytes per tile buffer

#define FSCALE 8.0f                          // pre-scale before fp8 quant
#define EXPF   (2.0f / (FSCALE * FSCALE))    // exp(2*dot) = exp(acc * EXPF)

typedef int   intx4    __attribute__((ext_vector_type(4)));
typedef int   intx8    __attribute__((ext_vector_type(8)));
typedef float floatx16 __attribute__((ext_vector_type(16)));

__device__ __forceinline__ void async_ld16(const void* g, void* l) {
    __builtin_amdgcn_global_load_lds(
        (__attribute__((address_space(1))) void*)(void*)g,
        (__attribute__((address_space(3))) void*)l,
        16, 0, 0);
}

// ------------- row L2-normalize: fp32 -> fp8 e4m3 (x FSCALE) -------------
__global__ __launch_bounds__(256) void norm_kernel(const float* __restrict__ text,
                                                   const float* __restrict__ image,
                                                   unsigned char* __restrict__ out) {
    const int fsel = blockIdx.y;
    const float* in = fsel ? image : text;
    unsigned char* o = out + (size_t)fsel * BATCH * DIM;
    const int row = blockIdx.x;
    const int t   = threadIdx.x;
    const float4* src = (const float4*)(in + (size_t)row * DIM);
    float4 v = src[t];
    float ss = v.x * v.x + v.y * v.y + v.z * v.z + v.w * v.w;
    #pragma unroll
    for (int m = 32; m >= 1; m >>= 1) ss += __shfl_xor(ss, m);
    __shared__ float red[4];
    if ((t & 63) == 0) red[t >> 6] = ss;
    __syncthreads();
    const float n2  = red[0] + red[1] + red[2] + red[3];
    const float inv = FSCALE / fmaxf(sqrtf(n2), 1e-12f);
    int p = __builtin_amdgcn_cvt_pk_fp8_f32(v.x * inv, v.y * inv, 0, false);
    p     = __builtin_amdgcn_cvt_pk_fp8_f32(v.z * inv, v.w * inv, p, true);
    ((int*)(o + (size_t)row * DIM))[t] = p;
}

// -------- fused symmetric sim GEMM (MX-fp8, unit scales) + exp + dual sum --------
// 256 threads / 4 waves, per-wave 64x64 via mfma_scale_f32_32x32x64_f8f6f4
// (frag regs 96->64 vs 16x16 shape; demand ~170 fits the 2-block 256-VGPR
// budget naturally -- NO occupancy attributes, r5/r7/r8 all spilled).
// K-loop: double-buffered LDS, ONE barrier/iter, order
//   [barrier][ds_read ALL frags][issue next staging][MFMAs]
// so no ds_read ever follows a staging issue (kills the compiler's
// conservative vmcnt(0)-before-ds_read that serialized r4/r6), and the
// staging drain at the next barrier lands after a full MFMA+read window.
__global__ __launch_bounds__(256)
void sim_kernel(const unsigned char* __restrict__ F,
                const int* __restrict__ label,
                float* __restrict__ S) {
    // band tables: bj in [bs[x], be[x]); bn[x] = tiles in band
    const int bs[8] = {0, 23, 32, 40, 46, 51, 56, 60};
    const int be[8] = {23, 32, 40, 46, 51, 56, 60, 64};
    const int bn[8] = {276, 252, 292, 261, 245, 270, 234, 250};

    const int x = blockIdx.x & 7;       // XCD (round-robin dispatch heuristic)
    const int l = blockIdx.x >> 3;      // local index within band
    if (l >= bn[x]) return;             // padding block

    const int s = bs[x];
    const int w = be[x] - s;
    int bi, bj;
    const int nfull = s * w;
    if (l < nfull) {
        bi = l / w;
        bj = s + (l % w);
    } else {
        int l2 = l - nfull;
        int k = 0, width = w;
        while (l2 >= width) { l2 -= width; --width; ++k; }
        bi = s + k;
        bj = bi + l2;
    }
    const bool diag = (bi == bj);

    const int f = blockIdx.z;
    const unsigned char* A = F + (size_t)f * BATCH * DIM;
    float* SR = S + (size_t)f * 2 * BATCH;
    float* SN = SR + BATCH;

    const int rowTile = bi * 128;
    const int colTile = bj * 128;

    // double-buffered 128x128-byte tiles; 16-B chunk swizzle: chunk c of row r
    // stored at slot c ^ (r&7)  (staging + swizzle identical to r4, proven).
    __shared__ __align__(16) unsigned char As[2 * TILEB];
    __shared__ __align__(16) unsigned char Bs[2 * TILEB];

    const int tid  = threadIdx.x;
    const int lane = tid & 63;
    const int wave = tid >> 6;          // 0..3
    const int wm   = wave >> 1;         // 2x2 wave grid over the 128x128 tile
    const int wn   = wave & 1;
    const int rl   = lane & 31;         // 32x32 MFMA: m|n = lane&31
    const int h    = lane >> 5;         // k-half selector
    const int r7   = rl & 7;            // swizzle residue of the frag row

    // staging (r4 verbatim): wave covers rows wave*32..+32 via 4 issues of
    // 8 rows; lane -> row lane>>3, LDS slot lane&7 (HW: dest = base+lane*16),
    // global chunk = slot ^ (row&7)
    const int sRowOff = lane >> 3;            // 0..7
    const int chunk   = (lane & 7) ^ sRowOff; // (row&7) == sRowOff
    const unsigned char* gA = A + (size_t)(rowTile + wave * 32 + sRowOff) * DIM + chunk * 16;
    const unsigned char* gB = A + (size_t)(colTile + wave * 32 + sRowOff) * DIM + chunk * 16;
    const int lOff = wave * 32 * 128 + lane * 16;   // within a tile buffer

    floatx16 acc[2][2];
    #pragma unroll
    for (int mi = 0; mi < 2; ++mi)
        #pragma unroll
        for (int ni = 0; ni < 2; ++ni)
            #pragma unroll
            for (int r = 0; r < 16; ++r) acc[mi][ni][r] = 0.f;

// read one 32x32x64 fragment: row = ROWOFF + rl, k-half h, k-sub KS;
// 32 bytes = chunks (4*KS + 2h, 4*KS + 2h + 1), un-swizzled by ^r7.
#define READF(DST, TILE, ROWOFF, KS)                                            \
    {                                                                           \
        const unsigned char* rbase = (TILE) + (size_t)((ROWOFF) + rl) * 128;    \
        const int c0 = 4 * (KS) + 2 * h;                                        \
        intx4 lo = *(const intx4*)(rbase + ((c0 ^ r7) * 16));                   \
        intx4 hi = *(const intx4*)(rbase + (((c0 + 1) ^ r7) * 16));             \
        DST = __builtin_shufflevector(lo, hi, 0, 1, 2, 3, 4, 5, 6, 7);          \
    }

    // preload tile 0 into buffer 0
    #pragma unroll
    for (int t = 0; t < 4; ++t) {
        async_ld16(gA + (size_t)t * 8 * DIM, As + lOff + t * 1024);
        async_ld16(gB + (size_t)t * 8 * DIM, Bs + lOff + t * 1024);
    }
    gA += 128; gB += 128;

    for (int k0 = 0; k0 < DIM; k0 += 128) {
        const int cur = (k0 >> 7) & 1;
        __syncthreads();   // buffer `cur` fully populated (vmcnt drains here,
                           // a full MFMA+read window after the staging issue)

        const unsigned char* bufA = As + cur * TILEB;
        const unsigned char* bufB = Bs + cur * TILEB;

        // 1) read ALL fragments of the current buffer (no ds_read after this)
        intx8 af[2][2], bf[2][2];
        #pragma unroll
        for (int mi = 0; mi < 2; ++mi)
            #pragma unroll
            for (int ks = 0; ks < 2; ++ks)
                READF(af[mi][ks], bufA, wm * 64 + mi * 32, ks)
        #pragma unroll
        for (int ni = 0; ni < 2; ++ni)
            #pragma unroll
            for (int ks = 0; ks < 2; ++ks)
                READF(bf[ni][ks], bufB, wn * 64 + ni * 32, ks)

        // 2) THEN issue next tile into the idle buffer
        if (k0 + 128 < DIM) {
            const int nxt = cur ^ 1;
            #pragma unroll
            for (int t = 0; t < 4; ++t) {
                async_ld16(gA + (size_t)t * 8 * DIM, As + nxt * TILEB + lOff + t * 1024);
                async_ld16(gB + (size_t)t * 8 * DIM, Bs + nxt * TILEB + lOff + t * 1024);
            }
            gA += 128; gB += 128;
        }

        // 3) MFMAs (K=64 each, 2 k-subs)
        #pragma unroll
        for (int mi = 0; mi < 2; ++mi)
            #pragma unroll
            for (int ni = 0; ni < 2; ++ni) {
                acc[mi][ni] = __builtin_amdgcn_mfma_scale_f32_32x32x64_f8f6f4(
                    af[mi][0], bf[ni][0], acc[mi][ni],
                    0, 0, 0, 0x7F7F7F7F, 0, 0x7F7F7F7F);
                acc[mi][ni] = __builtin_amdgcn_mfma_scale_f32_32x32x64_f8f6f4(
                    af[mi][1], bf[ni][1], acc[mi][ni],
                    0, 0, 0, 0x7F7F7F7F, 0, 0x7F7F7F7F);
            }
    }

    // ---- epilogue: e = exp(acc*EXPF), eye mask, dual row/col sums ----
    // 32x32 C/D layout (guide-verified): col = lane&31,
    // row = (reg&3) + 8*(reg>>2) + 4*(lane>>5), reg in [0,16).
    int   colg[2];
    float wRc[2];
    #pragma unroll
    for (int ni = 0; ni < 2; ++ni) {
        colg[ni] = colTile + wn * 64 + ni * 32 + rl;
        wRc[ni]  = (label[colg[ni]] != 0) ? 1.0f : 0.0f;
    }

    float ccR[2] = {0.f, 0.f};
    float ccN[2] = {0.f, 0.f};

    #pragma unroll
    for (int mi = 0; mi < 2; ++mi) {
        #pragma unroll
        for (int reg = 0; reg < 16; ++reg) {
            const int rowg = rowTile + wm * 64 + mi * 32 +
                             (reg & 3) + 8 * (reg >> 2) + 4 * h;
            const float wRr = (label[rowg] != 0) ? 1.0f : 0.0f;
            float pR = 0.f, pN = 0.f;
            #pragma unroll
            for (int ni = 0; ni < 2; ++ni) {
                float c = acc[mi][ni][reg];
                float e = __expf(c * EXPF);
                if (diag) e = (rowg == colg[ni]) ? 0.0f : e;      // eye mask
                pR += wRc[ni] * e;
                pN += (1.0f - wRc[ni]) * e;
                ccR[ni] += wRr * e;
                ccN[ni] += (1.0f - wRr) * e;
            }
            // row sum: reduce over the 32 lanes of this half (cols 0..31+ni*32)
            #pragma unroll
            for (int m = 1; m < 32; m <<= 1) {
                pR += __shfl_xor(pR, m);
                pN += __shfl_xor(pN, m);
            }
            if (rl == 0) {   // lanes 0 and 32 commit their half's row
                atomicAdd(&SR[rowg], pR);
                atomicAdd(&SN[rowg], pN);
            }
        }
    }

    if (!diag) {
        // column part: in-lane sums over (mi,reg) cover 32 of the wave's 64
        // rows; the other half-wave has the remaining rows -> xor 32.
        #pragma unroll
        for (int ni = 0; ni < 2; ++ni) {
            float cR = ccR[ni] + __shfl_xor(ccR[ni], 32);
            float cN = ccN[ni] + __shfl_xor(ccN[ni], 32);
            if (h == 0) {
                atomicAdd(&SR[colg[ni]], cR);
                atomicAdd(&SN[colg[ni]], cN);
            }
        }
    }
}

// ---------------- final per-row loss + global reduce ----------------
__global__ __launch_bounds__(256) void loss_kernel(const float* __restrict__ S,
                                                   const int* __restrict__ label,
                                                   float* __restrict__ out) {
    const int i = blockIdx.x * 256 + threadIdx.x;   // 0..8191
    const int lab = label[i];
    float t = 0.f;
    #pragma unroll
    for (int f = 0; f < 2; ++f) {
        const float* SR = S + (size_t)f * 2 * BATCH;
        const float* SN = SR + BATCH;
        const float own = lab ? SR[i] : SN[i];
        const float oth = lab ? SN[i] : SR[i];
        t += -logf(own / (own + oth) + 1e-8f);
    }
    t *= (1.0f / 4096.0f);
    #pragma unroll
    for (int m = 32; m >= 1; m >>= 1) t += __shfl_xor(t, m);
    __shared__ float red[4];
    if ((threadIdx.x & 63) == 0) red[threadIdx.x >> 6] = t;
    __syncthreads();
    if (threadIdx.x == 0) atomicAdd(out, red[0] + red[1] + red[2] + red[3]);
}

extern "C" void kernel_launch(void* const* d_in, const int* in_sizes, int n_in,
                              void* d_out, int out_size, void* d_ws, size_t ws_size,
                              hipStream_t stream) {
    const float* text  = (const float*)d_in[0];
    const float* image = (const float*)d_in[1];
    const int*   label = (const int*)d_in[2];
    float* out = (float*)d_out;

    // workspace: Fn[2][8192][1024] fp8 (16 MB), then S[2][2][8192] f32
    unsigned char* Fn = (unsigned char*)d_ws;
    float* S = (float*)((char*)d_ws + (size_t)2 * BATCH * DIM);

    hipMemsetAsync(S, 0, (size_t)2 * 2 * BATCH * sizeof(float), stream);
    hipMemsetAsync(out, 0, sizeof(float), stream);

    dim3 ngrid(BATCH, 2);
    norm_kernel<<<ngrid, 256, 0, stream>>>(text, image, Fn);

    dim3 grid(GRIDX, 1, 2);
    sim_kernel<<<grid, 256, 0, stream>>>(Fn, label, S);

    loss_kernel<<<BATCH / 256, 256, 0, stream>>>(S, label, out);
}